// Round 1
// baseline (96.836 us; speedup 1.0000x reference)
//
#include <hip/hip_runtime.h>

typedef __attribute__((ext_vector_type(4))) float f32x4;
typedef __attribute__((ext_vector_type(8))) short bf16x8;
typedef __attribute__((ext_vector_type(4))) unsigned short u16x4;

#define NB 8
#define LLEN 512
#define DD 768
#define MW 12
#define HH 384
#define TT (NB * LLEN)      // 4096 tokens
#define SS (LLEN * MW)      // 6144 spans per batch
#define KP (3 * HH)         // 1152 packed-K (hi/lo 3-pass)

// ---------- helpers ----------
__device__ __forceinline__ unsigned short f2bf(float x) {
  unsigned u = __builtin_bit_cast(unsigned, x);
  u += 0x7fff + ((u >> 16) & 1);              // RNE
  return (unsigned short)(u >> 16);
}
__device__ __forceinline__ float bf2f(unsigned short b) {
  return __builtin_bit_cast(float, (unsigned)b << 16);
}
__device__ __forceinline__ void gload_lds16(const void* g, void* l) {
  __builtin_amdgcn_global_load_lds(
      (const __attribute__((address_space(1))) unsigned int*)g,
      (__attribute__((address_space(3))) unsigned int*)l, 16, 0, 0);
}

// ---------- pack h -> A'u, A'v (bf16, K'=1152: [hi | hi | lo]) ----------
__global__ __launch_bounds__(256) void pack_h_k(const float* __restrict__ h,
                                                unsigned short* __restrict__ Au,
                                                unsigned short* __restrict__ Av) {
  int idx = blockIdx.x * 256 + threadIdx.x;   // over TT*192 float4s
  int t = idx / 192;
  int k = (idx - t * 192) * 4;
  f32x4 f = *(const f32x4*)(h + (size_t)idx * 4);
  unsigned short* A = (k < HH) ? Au : Av;
  int kk = (k < HH) ? k : k - HH;
  u16x4 hi, lo;
#pragma unroll
  for (int j = 0; j < 4; ++j) {
    float x = f[j];
    unsigned short hb = f2bf(x);
    hi[j] = hb;
    lo[j] = f2bf(x - bf2f(hb));
  }
  unsigned short* base = A + (size_t)t * KP + kk;
  *(u16x4*)(base) = hi;
  *(u16x4*)(base + HH) = hi;
  *(u16x4*)(base + 2 * HH) = lo;
}

// ---------- pack W -> B'u, B'v (bf16, K'=1152: [hi | lo | hi]) ----------
__global__ __launch_bounds__(256) void pack_w_k(const float* __restrict__ W,
                                                unsigned short* __restrict__ Bu,
                                                unsigned short* __restrict__ Bv) {
  int idx = blockIdx.x * 256 + threadIdx.x;   // over DD*192 float4s
  int e = idx / 192;
  int k = (idx - e * 192) * 4;
  f32x4 f = *(const f32x4*)(W + (size_t)idx * 4);
  unsigned short* Bm = (k < HH) ? Bu : Bv;
  int kk = (k < HH) ? k : k - HH;
  u16x4 hi, lo;
#pragma unroll
  for (int j = 0; j < 4; ++j) {
    float x = f[j];
    unsigned short hb = f2bf(x);
    hi[j] = hb;
    lo[j] = f2bf(x - bf2f(hb));
  }
  unsigned short* base = Bm + (size_t)e * KP + kk;
  *(u16x4*)(base) = hi;
  *(u16x4*)(base + HH) = lo;
  *(u16x4*)(base + 2 * HH) = hi;
}

// ---------- sentinel projections: us[e]=ss@W[e,:384], vs[e]=es@W[e,384:] ----------
__global__ __launch_bounds__(64) void sent_k(const float* __restrict__ ss,
                                             const float* __restrict__ es,
                                             const float* __restrict__ W,
                                             float* __restrict__ us, float* __restrict__ vs) {
  int e = blockIdx.x;
  int lane = threadIdx.x;
  float a = 0.f, b = 0.f;
  const float* w = W + (size_t)e * DD;
  for (int j = lane; j < HH; j += 64) {
    a += ss[j] * w[j];
    b += es[j] * w[HH + j];
  }
#pragma unroll
  for (int off = 32; off > 0; off >>= 1) {
    a += __shfl_down(a, off);
    b += __shfl_down(b, off);
  }
  if (lane == 0) { us[e] = a; vs[e] = b; }
}

// ---------- bf16 GEMM: C[M=4096][N=768] = A'[M][K'] * B'^T[N][K'] ----------
__global__ __launch_bounds__(256) void gemm_k(const unsigned short* __restrict__ Au,
                                              const unsigned short* __restrict__ Bu,
                                              const unsigned short* __restrict__ Av,
                                              const unsigned short* __restrict__ Bv,
                                              float* __restrict__ Uo, float* __restrict__ Vo) {
  const unsigned short* A;
  const unsigned short* Bm;
  float* C;
  if (blockIdx.z == 0) { A = Au; Bm = Bu; C = Uo; }
  else                 { A = Av; Bm = Bv; C = Vo; }

  __shared__ unsigned short As[128 * 64];   // 16 KB
  __shared__ unsigned short Bs[128 * 64];   // 16 KB

  const int tid = threadIdx.x;
  const int lane = tid & 63;
  const int w = tid >> 6;
  const int wr = w >> 1, wc = w & 1;        // 2x2 waves -> 64x64 each
  const int l16 = lane & 15, l4 = lane >> 4;
  const int row0 = blockIdx.x * 128;
  const int col0 = blockIdx.y * 128;

  f32x4 acc[4][4] = {};
  const char* Ab = (const char*)A;
  const char* Bb = (const char*)Bm;

  for (int k0 = 0; k0 < KP; k0 += 64) {
    // stage 128x64 bf16 tiles of A and B^T via global_load_lds (16B/lane)
#pragma unroll
    for (int r = 0; r < 4; ++r) {
      int o = (r * 256 + tid) * 16;         // byte offset in 16 KB tile
      int row = o >> 7, colb = o & 127;     // 128 B per row
      gload_lds16(Ab + ((size_t)(row0 + row) * KP + k0) * 2 + colb, (char*)As + o);
    }
#pragma unroll
    for (int r = 0; r < 4; ++r) {
      int o = (r * 256 + tid) * 16;
      int row = o >> 7, colb = o & 127;
      gload_lds16(Bb + ((size_t)(col0 + row) * KP + k0) * 2 + colb, (char*)Bs + o);
    }
    __syncthreads();

    bf16x8 af[2][4], bfr[2][4];
#pragma unroll
    for (int ks = 0; ks < 2; ++ks)
#pragma unroll
      for (int m = 0; m < 4; ++m)
        af[ks][m] = *(const bf16x8*)&As[(wr * 64 + m * 16 + l16) * 64 + ks * 32 + l4 * 8];
#pragma unroll
    for (int ks = 0; ks < 2; ++ks)
#pragma unroll
      for (int n = 0; n < 4; ++n)
        bfr[ks][n] = *(const bf16x8*)&Bs[(wc * 64 + n * 16 + l16) * 64 + ks * 32 + l4 * 8];

#pragma unroll
    for (int m = 0; m < 4; ++m)
#pragma unroll
      for (int n = 0; n < 4; ++n) {
        acc[m][n] = __builtin_amdgcn_mfma_f32_16x16x32_bf16(af[0][m], bfr[0][n], acc[m][n], 0, 0, 0);
        acc[m][n] = __builtin_amdgcn_mfma_f32_16x16x32_bf16(af[1][m], bfr[1][n], acc[m][n], 0, 0, 0);
      }
    __syncthreads();
  }

  // epilogue: D row=(lane>>4)*4+reg, col=lane&15 (m89-verified)
#pragma unroll
  for (int m = 0; m < 4; ++m) {
    int grow = row0 + wr * 64 + m * 16 + l4 * 4;
#pragma unroll
    for (int n = 0; n < 4; ++n) {
      int gcol = col0 + wc * 64 + n * 16 + l16;
#pragma unroll
      for (int r = 0; r < 4; ++r)
        C[(size_t)(grow + r) * DD + gcol] = acc[m][n][r];
    }
  }
}

// ---------- assembly: out = relu(U[end] + Vnext - Uprev - V[start] + b) ----------
__global__ __launch_bounds__(192) void assemble_k(const int* __restrict__ span,
                                                  const float* __restrict__ U,
                                                  const float* __restrict__ V,
                                                  const float* __restrict__ us,
                                                  const float* __restrict__ vs,
                                                  const float* __restrict__ bias,
                                                  float* __restrict__ out) {
  const int bs = blockIdx.x;                 // 0 .. NB*SS-1
  const int b = bs / SS;
  const int t0 = b * LLEN;
  const int start = span[(size_t)bs * 2 + 0];
  const int end   = span[(size_t)bs * 2 + 1];
  const int e4 = threadIdx.x;                // 0..191
  const f32x4* U4 = (const f32x4*)U;
  const f32x4* V4 = (const f32x4*)V;

  f32x4 pe = U4[(size_t)(t0 + end) * 192 + e4];
  f32x4 pv = (end + 1 >= LLEN) ? ((const f32x4*)vs)[e4]
                               : V4[(size_t)(t0 + end + 1) * 192 + e4];
  f32x4 mu = (start == 0) ? ((const f32x4*)us)[e4]
                          : U4[(size_t)(t0 + start - 1) * 192 + e4];
  f32x4 mv = V4[(size_t)(t0 + start) * 192 + e4];
  f32x4 bb = ((const f32x4*)bias)[e4];
  f32x4 r = pe + pv - mu - mv + bb;
#pragma unroll
  for (int j = 0; j < 4; ++j) r[j] = fmaxf(r[j], 0.f);
  ((f32x4*)out)[(size_t)bs * 192 + e4] = r;
}

// ---------- naive fallback (only if ws too small) ----------
__global__ __launch_bounds__(256) void naive_k(const float* __restrict__ h,
                                               const int* __restrict__ span,
                                               const float* __restrict__ W,
                                               const float* __restrict__ bias,
                                               const float* __restrict__ ss,
                                               const float* __restrict__ es,
                                               float* __restrict__ out) {
  int bs = blockIdx.x;
  int b = bs / SS;
  int start = span[(size_t)bs * 2 + 0];
  int end   = span[(size_t)bs * 2 + 1];
  __shared__ float rep[DD];
  const float* hb = h + (size_t)b * LLEN * DD;
  for (int k = threadIdx.x; k < HH; k += blockDim.x) {
    float fs = (start == 0) ? ss[k] : hb[(size_t)(start - 1) * DD + k];
    rep[k] = hb[(size_t)end * DD + k] - fs;
    float bstart = (end + 1 >= LLEN) ? es[k] : hb[(size_t)(end + 1) * DD + HH + k];
    rep[HH + k] = bstart - hb[(size_t)start * DD + HH + k];
  }
  __syncthreads();
  for (int e = threadIdx.x; e < DD; e += blockDim.x) {
    const float* w = W + (size_t)e * DD;
    float acc = bias[e];
    for (int k = 0; k < DD; k += 4) {
      acc += rep[k] * w[k] + rep[k + 1] * w[k + 1] + rep[k + 2] * w[k + 2] + rep[k + 3] * w[k + 3];
    }
    out[(size_t)bs * DD + e] = fmaxf(acc, 0.f);
  }
}

extern "C" void kernel_launch(void* const* d_in, const int* in_sizes, int n_in,
                              void* d_out, int out_size, void* d_ws, size_t ws_size,
                              hipStream_t stream) {
  const float* h  = (const float*)d_in[0];
  const int* span = (const int*)d_in[1];
  const float* W  = (const float*)d_in[2];
  const float* bias = (const float*)d_in[3];
  const float* ss = (const float*)d_in[4];
  const float* es = (const float*)d_in[5];
  float* out = (float*)d_out;

  const size_t szU  = (size_t)TT * DD * sizeof(float);            // 12.58 MB
  const size_t szA  = (size_t)TT * KP * sizeof(unsigned short);   // 9.44 MB
  const size_t szB  = (size_t)DD * KP * sizeof(unsigned short);   // 1.77 MB
  const size_t szS  = DD * sizeof(float);
  const size_t need = 2 * szU + 2 * szA + 2 * szB + 2 * szS;      // ~47.6 MB

  if (ws_size < need) {
    naive_k<<<NB * SS, 256, 0, stream>>>(h, span, W, bias, ss, es, out);
    return;
  }

  char* ws = (char*)d_ws;
  float* U = (float*)ws;
  float* V = (float*)(ws + szU);
  unsigned short* Au = (unsigned short*)(ws + 2 * szU);
  unsigned short* Av = (unsigned short*)(ws + 2 * szU + szA);
  unsigned short* Bu = (unsigned short*)(ws + 2 * szU + 2 * szA);
  unsigned short* Bv = (unsigned short*)(ws + 2 * szU + 2 * szA + szB);
  float* us = (float*)(ws + 2 * szU + 2 * szA + 2 * szB);
  float* vs = us + DD;

  pack_h_k<<<(TT * 192) / 256, 256, 0, stream>>>(h, Au, Av);
  pack_w_k<<<(DD * 192) / 256, 256, 0, stream>>>(W, Bu, Bv);
  sent_k<<<DD, 64, 0, stream>>>(ss, es, W, us, vs);
  gemm_k<<<dim3(TT / 128, DD / 128, 2), 256, 0, stream>>>(Au, Bu, Av, Bv, U, V);
  assemble_k<<<NB * SS, 192, 0, stream>>>(span, U, V, us, vs, bias, out);
}